// Round 6
// baseline (1201.218 us; speedup 1.0000x reference)
//
#include <hip/hip_runtime.h>
#include <math.h>

// ComplexPolarTransformerBeta — round 6: spill elimination.
// vs R5: (1) amdgpu_waves_per_eu(2,2) — LDS caps us at 8 waves/CU = 2/EU, so
// set the allocator's occupancy TARGET (launch_bounds only sets a minimum;
// the heuristic kept targeting 4 waves/EU -> 128 regs -> ~1 GB scratch).
// (2) #pragma unroll 2 on GEMM kb-loops (full unroll hoisted ~64 live operand
// regs). (3) embedding weight cache halved (two column-half passes).

typedef __attribute__((ext_vector_type(8)))  short s16x8;
typedef __attribute__((ext_vector_type(16))) float f32x16;

#define STR  136      // LDS row stride (shorts / floats): 128 data + 8 pad
#define LOFS 17408    // offset of lo-array within a region (128*136 shorts)
#define MFMA(a, b, c) __builtin_amdgcn_mfma_f32_32x32x16_bf16(a, b, c, 0, 0, 0)
#define ROWP(reg) (((reg) & 3) + (((reg) >> 2) << 3) + (h5 << 2))

__device__ __forceinline__ unsigned short bfhi(float x) {
  unsigned u = __float_as_uint(x);
  return (unsigned short)((u + 0x7FFFu + ((u >> 16) & 1u)) >> 16);
}
__device__ __forceinline__ float bf2f(unsigned short h) {
  return __uint_as_float(((unsigned)h) << 16);
}

// Stage C-layout acc into S[row=n][col=m] bf16 hi/lo (packed b64 over reg-quads).
__device__ __forceinline__ void stageB64(short* SH, const f32x16 acc[2],
                                         int nb0, int l31, int h5, int mblk, float scl) {
  #pragma unroll
  for (int tl = 0; tl < 2; ++tl) {
    int row = nb0 + 32 * tl + l31;
    #pragma unroll
    for (int q = 0; q < 4; ++q) {
      int col = mblk + 8 * q + 4 * h5;
      float v0 = acc[tl][4*q+0] * scl, v1 = acc[tl][4*q+1] * scl;
      float v2 = acc[tl][4*q+2] * scl, v3 = acc[tl][4*q+3] * scl;
      unsigned short h0 = bfhi(v0), h1 = bfhi(v1), h2 = bfhi(v2), h3 = bfhi(v3);
      short4 hv = make_short4((short)h0, (short)h1, (short)h2, (short)h3);
      short4 lv = make_short4((short)bfhi(v0 - bf2f(h0)), (short)bfhi(v1 - bf2f(h1)),
                              (short)bfhi(v2 - bf2f(h2)), (short)bfhi(v3 - bf2f(h3)));
      *(short4*)(SH + row * STR + col) = hv;
      *(short4*)(SH + LOFS + row * STR + col) = lv;
    }
  }
}

// Stage per-thread state v[32] (C-layout) into S[a][h] bf16 hi/lo.
__device__ __forceinline__ void stageScatter(short* SH, const float* v,
                                             int nb0, int l31, int h5, int mblk) {
  #pragma unroll
  for (int tl = 0; tl < 2; ++tl) {
    int col = nb0 + 32 * tl + l31;
    #pragma unroll
    for (int reg = 0; reg < 16; ++reg) {
      int row = mblk + ROWP(reg);
      float x = v[tl * 16 + reg];
      unsigned short h = bfhi(x);
      SH[row * STR + col] = (short)h;
      SH[LOFS + row * STR + col] = (short)bfhi(x - bf2f(h));
    }
  }
}

// D[m][n] += A(LDS)[m][k] * B(LDS)^T[k][n]  (both [row][k-contig] bf16 hi/lo)
__device__ __forceinline__ void gemmLL(f32x16 acc[2], const short* AH, const short* BH,
                                       int mblk, int nb0, int l31, int h5) {
  int arow = mblk + l31;
  #pragma unroll 2
  for (int kb = 0; kb < 8; ++kb) {
    int k0 = kb * 16 + 8 * h5;
    s16x8 ah = *(const s16x8*)(AH + arow * STR + k0);
    s16x8 al = *(const s16x8*)(AH + LOFS + arow * STR + k0);
    #pragma unroll
    for (int tl = 0; tl < 2; ++tl) {
      int brow = nb0 + 32 * tl + l31;
      s16x8 bh = *(const s16x8*)(BH + brow * STR + k0);
      s16x8 bl = *(const s16x8*)(BH + LOFS + brow * STR + k0);
      acc[tl] = MFMA(ah, bh, acc[tl]);
      acc[tl] = MFMA(ah, bl, acc[tl]);
      acc[tl] = MFMA(al, bh, acc[tl]);
    }
  }
}

// D[m=a][n=h]: A = LDS activation rows, B = preprocessed weight (frag-ordered).
__device__ __forceinline__ void gemmNW(f32x16 acc[2], const short* AH, const short* W,
                                       int mblk, int w1, int l31, int h5, int lane) {
  int arow = mblk + l31;
  #pragma unroll 2
  for (int kb = 0; kb < 8; ++kb) {
    int k0 = kb * 16 + 8 * h5;
    s16x8 ah = *(const s16x8*)(AH + arow * STR + k0);
    s16x8 al = *(const s16x8*)(AH + LOFS + arow * STR + k0);
    #pragma unroll
    for (int tl = 0; tl < 2; ++tl) {
      int hblk = 2 * w1 + tl;
      const short* wp = W + (((hblk * 8 + kb) * 64 + lane) * 8);
      s16x8 bh = *(const s16x8*)wp;
      s16x8 bl = *(const s16x8*)(wp + 32768);
      acc[tl] = MFMA(ah, bh, acc[tl]);
      acc[tl] = MFMA(ah, bl, acc[tl]);
      acc[tl] = MFMA(al, bh, acc[tl]);
    }
  }
}

// D[m=h][n=i]: A = preprocessed weight (m-tile = w>>1), B = LDS activation rows.
__device__ __forceinline__ void gemmTW(f32x16 acc[2], const short* W, const short* BH,
                                       int mt, int nb0, int l31, int h5, int lane) {
  #pragma unroll 2
  for (int kb = 0; kb < 8; ++kb) {
    int k0 = kb * 16 + 8 * h5;
    const short* wp = W + (((mt * 8 + kb) * 64 + lane) * 8);
    s16x8 ah = *(const s16x8*)wp;
    s16x8 al = *(const s16x8*)(wp + 32768);
    #pragma unroll
    for (int tl = 0; tl < 2; ++tl) {
      int brow = nb0 + 32 * tl + l31;
      s16x8 bh = *(const s16x8*)(BH + brow * STR + k0);
      s16x8 bl = *(const s16x8*)(BH + LOFS + brow * STR + k0);
      acc[tl] = MFMA(ah, bh, acc[tl]);
      acc[tl] = MFMA(ah, bl, acc[tl]);
      acc[tl] = MFMA(al, bh, acc[tl]);
    }
  }
}

// ---------------- weight preprocessing ----------------
__global__ __launch_bounds__(512)
void prep_kernel(const float* __restrict__ Wq, const float* __restrict__ Wk,
                 const float* __restrict__ Wvm, const float* __restrict__ Wvp,
                 const float* __restrict__ rp_W, short* __restrict__ ws) {
  int mid = blockIdx.x >> 2, hblk = blockIdx.x & 3;
  int kb = threadIdx.x >> 6, lane = threadIdx.x & 63;
  const float* src;
  if (mid < 4)       src = Wq  + mid * 16384;
  else if (mid < 8)  src = Wk  + (mid - 4) * 16384;
  else if (mid < 12) src = Wvm + (mid - 8) * 16384;
  else if (mid < 16) src = Wvp + (mid - 12) * 16384;
  else if (mid == 16) src = rp_W;
  else                src = rp_W + 16384;
  int h = hblk * 32 + (lane & 31);
  int kbase = kb * 16 + ((lane >> 5) << 3);
  s16x8 H, L;
  #pragma unroll
  for (int j = 0; j < 8; ++j) {
    float v = src[(size_t)(kbase + j) * 128 + h];
    unsigned short hi = bfhi(v);
    H[j] = (short)hi;
    L[j] = (short)bfhi(v - bf2f(hi));
  }
  short* dst = ws + (size_t)mid * 65536 + ((hblk * 8 + kb) * 64 + lane) * 8;
  *(s16x8*)dst = H;
  *(s16x8*)(dst + 32768) = L;
}

// ---------------- main kernel ----------------
__global__ __launch_bounds__(512)
__attribute__((amdgpu_waves_per_eu(2, 2)))
void cpt_kernel(const float* __restrict__ atom_types,
                const float* __restrict__ coords,
                const int*   __restrict__ edge_index,
                const float* __restrict__ edge_attr,
                const float* __restrict__ emb_Wm, const float* __restrict__ emb_bm,
                const float* __restrict__ emb_Wp, const float* __restrict__ emb_bp,
                const float* __restrict__ bq, const float* __restrict__ bk,
                const float* __restrict__ bvm, const float* __restrict__ bvp,
                const float* __restrict__ We,  const float* __restrict__ be,
                const float* __restrict__ dist_scale,
                const float* __restrict__ ln_g, const float* __restrict__ ln_b,
                const float* __restrict__ rp_b,
                const float* __restrict__ h1_W, const float* __restrict__ h1_b,
                const float* __restrict__ h2_W, const float* __restrict__ h2_b,
                const short* __restrict__ wpre,
                float* __restrict__ out)
{
  __shared__ __align__(16) short R1s[34816];
  __shared__ __align__(16) short R2s[34816];
  __shared__ float SCa[512];
  __shared__ float SCb[512];

  const int t = threadIdx.x, b = blockIdx.x;
  const int w = t >> 6, lane = t & 63, l31 = lane & 31, h5 = lane >> 5;
  const int mblk = (w >> 1) << 5;
  const int w1 = w & 1;
  const int nb0 = w1 << 6;
  const float scale = 0.08838834764831845f;  // 1/sqrt(128)

  // ---- edge gather (layer-invariant) ----
  int efA, efB; float4 eaA, eaB;
  {
    int e0 = t, e1 = t + 512;
    int i0 = edge_index[(size_t)b * 2048 + e0];
    int j0 = edge_index[(size_t)b * 2048 + 1024 + e0];
    int i1 = edge_index[(size_t)b * 2048 + e1];
    int j1 = edge_index[(size_t)b * 2048 + 1024 + e1];
    efA = i0 * STR + j0;  efB = i1 * STR + j1;
    eaA = *(const float4*)(edge_attr + ((size_t)b * 1024 + e0) * 4);
    eaB = *(const float4*)(edge_attr + ((size_t)b * 1024 + e1) * 4);
  }

  // ---- embedding -> magP/phP (C-layout), two column-half passes ----
  float magP[32], phP[32];
  #pragma unroll 1
  for (int half = 0; half < 2; ++half) {
    int hcol = nb0 + 32 * half + l31;
    float wmv[19], wpv[19];
    #pragma unroll
    for (int d = 0; d < 19; ++d) {
      wmv[d] = emb_Wm[d * 128 + hcol];
      wpv[d] = emb_Wp[d * 128 + hcol];
    }
    float bm = emb_bm[hcol], bp = emb_bp[hcol];
    #pragma unroll
    for (int reg = 0; reg < 16; ++reg) {
      int a = mblk + ROWP(reg);
      const float* xr = atom_types + ((size_t)b * 128 + a) * 16;
      float x[19];
      float4 v0 = *(const float4*)xr,       v1 = *(const float4*)(xr + 4);
      float4 v2 = *(const float4*)(xr + 8), v3 = *(const float4*)(xr + 12);
      x[0]=v0.x; x[1]=v0.y; x[2]=v0.z; x[3]=v0.w;
      x[4]=v1.x; x[5]=v1.y; x[6]=v1.z; x[7]=v1.w;
      x[8]=v2.x; x[9]=v2.y; x[10]=v2.z; x[11]=v2.w;
      x[12]=v3.x; x[13]=v3.y; x[14]=v3.z; x[15]=v3.w;
      const float* cr = coords + ((size_t)b * 128 + a) * 3;
      x[16]=cr[0]; x[17]=cr[1]; x[18]=cr[2];
      float m0 = bm, p0 = bp;
      #pragma unroll
      for (int d = 0; d < 19; ++d) { m0 += x[d] * wmv[d]; p0 += x[d] * wpv[d]; }
      magP[half * 16 + reg] = m0;
      phP[half * 16 + reg]  = p0;
    }
  }

  // ---- layers ----
  for (int l = 0; l < 4; ++l) {
    const short* wqP  = wpre + (size_t)l * 65536;
    const short* wkP  = wpre + (size_t)(4 + l) * 65536;
    const short* wvmP = wpre + (size_t)(8 + l) * 65536;
    const short* wvpP = wpre + (size_t)(12 + l) * 65536;
    float we0 = We[l*4], we1 = We[l*4+1], we2 = We[l*4+2], we3 = We[l*4+3];
    float bel = be[l], dsl = dist_scale[l];

    __syncthreads();                       // prior readers of R1/R2 done
    float* biasF = (float*)R1s;            // fp32 [128][STR] bias matrix
    {
      float4* z4 = (float4*)R1s;
      #pragma unroll
      for (int k = 0; k < 9; ++k) { int idx = t + 512 * k; if (idx < 4352) z4[idx] = make_float4(0.f,0.f,0.f,0.f); }
    }
    __syncthreads();
    {
      float bvA = eaA.x*we0 + eaA.y*we1 + eaA.z*we2 + eaA.w*we3 + bel + dsl*eaA.x;
      float bvB = eaB.x*we0 + eaB.y*we1 + eaB.z*we2 + eaB.w*we3 + bel + dsl*eaB.x;
      atomicAdd(&biasF[efA], bvA);
      atomicAdd(&biasF[efB], bvB);
    }
    __syncthreads();
    // preload scores acc with bias (scoresT: m=j=mblk+ROWP, n=i=nb0+32tl+l31)
    f32x16 accS[2];
    #pragma unroll
    for (int tl = 0; tl < 2; ++tl) {
      int i = nb0 + 32 * tl + l31;
      #pragma unroll
      for (int reg = 0; reg < 16; ++reg)
        accS[tl][reg] = biasF[i * STR + (mblk + ROWP(reg))];
    }
    __syncthreads();                       // bias reads done
    stageScatter(R1s, magP, nb0, l31, h5, mblk);   // mag -> R1 [a][h]
    __syncthreads();

    // Q^T (D[h][i]) -> R2 scaled; then K^T (D[h][j])
    {
      f32x16 accQ[2];
      #pragma unroll
      for (int reg = 0; reg < 16; ++reg) {
        float bv = bq[l * 128 + mblk + ROWP(reg)];
        accQ[0][reg] = bv; accQ[1][reg] = bv;
      }
      gemmTW(accQ, wqP, R1s, w >> 1, nb0, l31, h5, lane);
      stageB64(R2s, accQ, nb0, l31, h5, mblk, scale);  // (scale*Q)[i][h] -> R2
    }
    f32x16 accK[2];
    {
      #pragma unroll
      for (int reg = 0; reg < 16; ++reg) {
        float bv = bk[l * 128 + mblk + ROWP(reg)];
        accK[0][reg] = bv; accK[1][reg] = bv;
      }
      gemmTW(accK, wkP, R1s, w >> 1, nb0, l31, h5, lane);
    }
    __syncthreads();                       // mag reads + Q writes done
    stageB64(R1s, accK, nb0, l31, h5, mblk, 1.0f);   // K[j][h] -> R1 (over mag)
    __syncthreads();

    // scoresT[j][i] = K @ (scale*Q)^T + bias
    gemmLL(accS, R1s, R2s, mblk, nb0, l31, h5);

    // softmax over j
    #pragma unroll
    for (int tl = 0; tl < 2; ++tl) {
      float m = accS[tl][0];
      #pragma unroll
      for (int reg = 1; reg < 16; ++reg) m = fmaxf(m, accS[tl][reg]);
      m = fmaxf(m, __shfl_xor(m, 32));
      if (h5 == 0) SCa[(w >> 1) * 128 + nb0 + 32 * tl + l31] = m;
    }
    __syncthreads();
    #pragma unroll
    for (int tl = 0; tl < 2; ++tl) {
      int i = nb0 + 32 * tl + l31;
      float mg = fmaxf(fmaxf(SCa[i], SCa[128 + i]), fmaxf(SCa[256 + i], SCa[384 + i]));
      float s = 0.f;
      #pragma unroll
      for (int reg = 0; reg < 16; ++reg) {
        float e = __expf(accS[tl][reg] - mg);
        accS[tl][reg] = e; s += e;
      }
      s += __shfl_xor(s, 32);
      if (h5 == 0) SCb[(w >> 1) * 128 + i] = s;
    }
    __syncthreads();
    #pragma unroll
    for (int tl = 0; tl < 2; ++tl) {
      int i = nb0 + 32 * tl + l31;
      float sg = SCb[i] + SCb[128 + i] + SCb[256 + i] + SCb[384 + i];
      float inv = 1.f / sg;
      #pragma unroll
      for (int reg = 0; reg < 16; ++reg) accS[tl][reg] *= inv;
    }
    __syncthreads();                       // scores reads of R1/R2 done
    stageB64(R2s, accS, nb0, l31, h5, mblk, 1.0f);   // attn[i][j] -> R2 (over Q)
    stageScatter(R1s, magP, nb0, l31, h5, mblk);     // mag -> R1 (over K)
    __syncthreads();

    // vm = mag @ Wvm
    {
      f32x16 accVM[2];
      #pragma unroll
      for (int tl = 0; tl < 2; ++tl) {
        float bv = bvm[l * 128 + nb0 + 32 * tl + l31];
        #pragma unroll
        for (int reg = 0; reg < 16; ++reg) accVM[tl][reg] = bv;
      }
      gemmNW(accVM, R1s, wvmP, mblk, w1, l31, h5, lane);
      __syncthreads();                     // mag reads done
      stageB64(R1s, accVM, nb0, l31, h5, mblk, 1.0f);  // vm[h][a] -> R1
      __syncthreads();
    }

    // new_mag = attn @ vm + mag
    f32x16 accM[2];
    #pragma unroll
    for (int tl = 0; tl < 2; ++tl)
      #pragma unroll
      for (int reg = 0; reg < 16; ++reg) accM[tl][reg] = magP[tl * 16 + reg];
    gemmLL(accM, R2s, R1s, mblk, nb0, l31, h5);

    // LayerNorm over h
    {
      float sv[16], qv[16];
      #pragma unroll
      for (int reg = 0; reg < 16; ++reg) {
        float a0 = accM[0][reg], a1 = accM[1][reg];
        float s = a0 + a1, q = a0 * a0 + a1 * a1;
        #pragma unroll
        for (int off = 1; off < 32; off <<= 1) { s += __shfl_xor(s, off); q += __shfl_xor(q, off); }
        sv[reg] = s; qv[reg] = q;
      }
      if (l31 == 0) {
        #pragma unroll
        for (int reg = 0; reg < 16; ++reg) {
          SCa[w * 32 + ROWP(reg)] = sv[reg];
          SCb[w * 32 + ROWP(reg)] = qv[reg];
        }
      }
      __syncthreads();
      float g0 = ln_g[l * 128 + nb0 + l31],      lb0 = ln_b[l * 128 + nb0 + l31];
      float g1 = ln_g[l * 128 + nb0 + 32 + l31], lb1 = ln_b[l * 128 + nb0 + 32 + l31];
      #pragma unroll
      for (int reg = 0; reg < 16; ++reg) {
        float s = sv[reg] + SCa[(w ^ 1) * 32 + ROWP(reg)];
        float q = qv[reg] + SCb[(w ^ 1) * 32 + ROWP(reg)];
        float mu = s * (1.f / 128.f);
        float var = q * (1.f / 128.f) - mu * mu;
        float inv = 1.f / sqrtf(var + 1e-5f);
        magP[reg]      = g0 * ((accM[0][reg] - mu) * inv) + lb0;
        magP[16 + reg] = g1 * ((accM[1][reg] - mu) * inv) + lb1;
      }
    }
    __syncthreads();                       // vm reads of R1 done
    stageScatter(R1s, phP, nb0, l31, h5, mblk);      // ph[a][h] -> R1
    __syncthreads();

    // vp = ph @ Wvp
    {
      f32x16 accV[2];
      #pragma unroll
      for (int tl = 0; tl < 2; ++tl) {
        float bv = bvp[l * 128 + nb0 + 32 * tl + l31];
        #pragma unroll
        for (int reg = 0; reg < 16; ++reg) accV[tl][reg] = bv;
      }
      gemmNW(accV, R1s, wvpP, mblk, w1, l31, h5, lane);
      __syncthreads();                     // ph reads done
      stageB64(R1s, accV, nb0, l31, h5, mblk, 1.0f); // vp[h][a] -> R1
      __syncthreads();
    }

    // new_ph = attn @ vp + ph
    f32x16 accP[2];
    #pragma unroll
    for (int tl = 0; tl < 2; ++tl)
      #pragma unroll
      for (int reg = 0; reg < 16; ++reg) accP[tl][reg] = phP[tl * 16 + reg];
    gemmLL(accP, R2s, R1s, mblk, nb0, l31, h5);
    #pragma unroll
    for (int tl = 0; tl < 2; ++tl)
      #pragma unroll
      for (int reg = 0; reg < 16; ++reg) phP[tl * 16 + reg] = accP[tl][reg];
  } // layers

  // ---- real/imag -> RealProjection ----
  float reB[32], imB[32];
  #pragma unroll
  for (int i = 0; i < 32; ++i) {
    float s_, c_;
    __sincosf(phP[i], &s_, &c_);
    reB[i] = magP[i] * c_;
    imB[i] = magP[i] * s_;
  }
  __syncthreads();
  stageScatter(R1s, reB, nb0, l31, h5, mblk);
  stageScatter(R2s, imB, nb0, l31, h5, mblk);
  __syncthreads();
  f32x16 accR[2];
  #pragma unroll
  for (int tl = 0; tl < 2; ++tl) {
    float bv = rp_b[nb0 + 32 * tl + l31];
    #pragma unroll
    for (int reg = 0; reg < 16; ++reg) accR[tl][reg] = bv;
  }
  gemmNW(accR, R1s, wpre + (size_t)16 * 65536, mblk, w1, l31, h5, lane);  // real @ rpA
  gemmNW(accR, R2s, wpre + (size_t)17 * 65536, mblk, w1, l31, h5, lane);  // imag @ rpB

  // ---- pooling (column sum over atoms) ----
  #pragma unroll
  for (int tl = 0; tl < 2; ++tl) {
    float ps = 0.f;
    #pragma unroll
    for (int reg = 0; reg < 16; ++reg) ps += accR[tl][reg];
    ps += __shfl_xor(ps, 32);
    if (h5 == 0) SCa[(w >> 1) * 128 + nb0 + 32 * tl + l31] = ps;
  }
  __syncthreads();
  if (t < 128) {
    float cs = SCa[t] + SCa[128 + t] + SCa[256 + t] + SCa[384 + t];
    SCb[t] = cs;
  }
  __syncthreads();
  if (t < 128) {
    float acc = h1_b[t];
    for (int i = 0; i < 128; ++i) {
      float cs = SCb[i];
      acc += cs * (h1_W[(size_t)i * 128 + t] * (1.f / 128.f) +
                   h1_W[(size_t)(128 + i) * 128 + t]);
    }
    float hv = acc / (1.f + __expf(-acc));   // SiLU
    SCb[128 + t] = hv * h2_W[t];
  }
  __syncthreads();
  if (t < 64) {
    float s2 = SCb[128 + t] + SCb[192 + t];
    #pragma unroll
    for (int off = 32; off >= 1; off >>= 1) s2 += __shfl_xor(s2, off);
    if (t == 0) out[b] = s2 + h2_b[0];
  }
}

extern "C" void kernel_launch(void* const* d_in, const int* in_sizes, int n_in,
                              void* d_out, int out_size, void* d_ws, size_t ws_size,
                              hipStream_t stream) {
  const float* atom_types = (const float*)d_in[0];
  const float* coords     = (const float*)d_in[1];
  const int*   edge_index = (const int*)  d_in[2];
  const float* edge_attr  = (const float*)d_in[3];
  const float* emb_Wm = (const float*)d_in[4];
  const float* emb_bm = (const float*)d_in[5];
  const float* emb_Wp = (const float*)d_in[6];
  const float* emb_bp = (const float*)d_in[7];
  const float* Wq  = (const float*)d_in[8];
  const float* bq  = (const float*)d_in[9];
  const float* Wk  = (const float*)d_in[10];
  const float* bk  = (const float*)d_in[11];
  const float* Wvm = (const float*)d_in[12];
  const float* bvm = (const float*)d_in[13];
  const float* Wvp = (const float*)d_in[14];
  const float* bvp = (const float*)d_in[15];
  const float* We  = (const float*)d_in[16];
  const float* be  = (const float*)d_in[17];
  const float* dist_scale = (const float*)d_in[18];
  const float* ln_g = (const float*)d_in[19];
  const float* ln_b = (const float*)d_in[20];
  const float* rp_W = (const float*)d_in[21];
  const float* rp_b = (const float*)d_in[22];
  const float* h1_W = (const float*)d_in[23];
  const float* h1_b = (const float*)d_in[24];
  const float* h2_W = (const float*)d_in[25];
  const float* h2_b = (const float*)d_in[26];
  float* out = (float*)d_out;
  short* wpre = (short*)d_ws;   // 18 matrices * 65536 shorts = 2.36 MB

  hipLaunchKernelGGL(prep_kernel, dim3(72), dim3(512), 0, stream,
                     Wq, Wk, Wvm, Wvp, rp_W, wpre);
  hipLaunchKernelGGL(cpt_kernel, dim3(1024), dim3(512), 0, stream,
                     atom_types, coords, edge_index, edge_attr,
                     emb_Wm, emb_bm, emb_Wp, emb_bp,
                     bq, bk, bvm, bvp,
                     We, be, dist_scale, ln_g, ln_b,
                     rp_b, h1_W, h1_b, h2_W, h2_b,
                     (const short*)wpre, out);
}

// Round 7
// 1103.557 us; speedup vs baseline: 1.0885x; 1.0885x over previous
//
#include <hip/hip_runtime.h>
#include <math.h>

// ComplexPolarTransformerBeta — round 7: fit the 128-VGPR budget.
// R4-R6 showed the allocator pins 128 arch VGPRs regardless of launch_bounds /
// waves_per_eu; per-thread state (mag[32]+ph[32]+accs) exceeded it -> ~1 GB
// scratch spill traffic = the runtime. Fix: 1024 threads = 16 waves, ONE 32x32
// MFMA tile per wave (mb = w>>2 rows, ncb = w&3 cols). Per-thread persistent
// state halves to magP[16]+phP[16]; peak live ~108 regs < 128. Same LDS
// regions/algebra as R6; occupancy doubles to 16 waves/CU.

typedef __attribute__((ext_vector_type(8)))  short s16x8;
typedef __attribute__((ext_vector_type(16))) float f32x16;

#define STR  136      // LDS row stride (shorts / floats): 128 data + 8 pad
#define LOFS 17408    // offset of lo-array within a region (128*136 shorts)
#define MFMA(a, b, c) __builtin_amdgcn_mfma_f32_32x32x16_bf16(a, b, c, 0, 0, 0)
#define ROWP(reg) (((reg) & 3) + (((reg) >> 2) << 3) + (h5 << 2))

__device__ __forceinline__ unsigned short bfhi(float x) {
  unsigned u = __float_as_uint(x);
  return (unsigned short)((u + 0x7FFFu + ((u >> 16) & 1u)) >> 16);
}
__device__ __forceinline__ float bf2f(unsigned short h) {
  return __uint_as_float(((unsigned)h) << 16);
}

// Stage C-layout acc (one 32x32 tile) into S[row=n][col=m] bf16 hi/lo.
__device__ __forceinline__ void stageB64(short* SH, const f32x16& acc,
                                         int ncb, int l31, int h5, int mblk, float scl) {
  int row = ncb * 32 + l31;
  #pragma unroll
  for (int q = 0; q < 4; ++q) {
    int col = mblk + 8 * q + 4 * h5;
    float v0 = acc[4*q+0] * scl, v1 = acc[4*q+1] * scl;
    float v2 = acc[4*q+2] * scl, v3 = acc[4*q+3] * scl;
    unsigned short h0 = bfhi(v0), h1 = bfhi(v1), h2 = bfhi(v2), h3 = bfhi(v3);
    short4 hv = make_short4((short)h0, (short)h1, (short)h2, (short)h3);
    short4 lv = make_short4((short)bfhi(v0 - bf2f(h0)), (short)bfhi(v1 - bf2f(h1)),
                            (short)bfhi(v2 - bf2f(h2)), (short)bfhi(v3 - bf2f(h3)));
    *(short4*)(SH + row * STR + col) = hv;
    *(short4*)(SH + LOFS + row * STR + col) = lv;
  }
}

// Stage per-thread state v[16] (C-layout tile) into S[a][h] bf16 hi/lo.
__device__ __forceinline__ void stageScatter(short* SH, const float* v,
                                             int ncb, int l31, int h5, int mblk) {
  int col = ncb * 32 + l31;
  #pragma unroll
  for (int reg = 0; reg < 16; ++reg) {
    int row = mblk + ROWP(reg);
    float x = v[reg];
    unsigned short h = bfhi(x);
    SH[row * STR + col] = (short)h;
    SH[LOFS + row * STR + col] = (short)bfhi(x - bf2f(h));
  }
}

// D[m][n] += A(LDS)[m][k] * B(LDS)[n][k]   (both [row][k-contig] bf16 hi/lo)
__device__ __forceinline__ void gemmLL(f32x16& acc, const short* AH, const short* BH,
                                       int mblk, int ncb, int l31, int h5) {
  int arow = mblk + l31, brow = ncb * 32 + l31;
  #pragma unroll 2
  for (int kb = 0; kb < 8; ++kb) {
    int k0 = kb * 16 + 8 * h5;
    s16x8 ah = *(const s16x8*)(AH + arow * STR + k0);
    s16x8 al = *(const s16x8*)(AH + LOFS + arow * STR + k0);
    s16x8 bh = *(const s16x8*)(BH + brow * STR + k0);
    s16x8 bl = *(const s16x8*)(BH + LOFS + brow * STR + k0);
    acc = MFMA(ah, bh, acc);
    acc = MFMA(ah, bl, acc);
    acc = MFMA(al, bh, acc);
  }
}

// D[m=a][n=h]: A = LDS activation rows, B = preprocessed weight (n-tile = ncb).
__device__ __forceinline__ void gemmNW(f32x16& acc, const short* AH, const short* W,
                                       int mblk, int ncb, int l31, int h5, int lane) {
  int arow = mblk + l31;
  #pragma unroll 2
  for (int kb = 0; kb < 8; ++kb) {
    int k0 = kb * 16 + 8 * h5;
    s16x8 ah = *(const s16x8*)(AH + arow * STR + k0);
    s16x8 al = *(const s16x8*)(AH + LOFS + arow * STR + k0);
    const short* wp = W + (((ncb * 8 + kb) * 64 + lane) * 8);
    s16x8 bh = *(const s16x8*)wp;
    s16x8 bl = *(const s16x8*)(wp + 32768);
    acc = MFMA(ah, bh, acc);
    acc = MFMA(ah, bl, acc);
    acc = MFMA(al, bh, acc);
  }
}

// D[m=h][n=i]: A = preprocessed weight (m-tile = mb), B = LDS activation rows.
__device__ __forceinline__ void gemmTW(f32x16& acc, const short* W, const short* BH,
                                       int mb, int ncb, int l31, int h5, int lane) {
  int brow = ncb * 32 + l31;
  #pragma unroll 2
  for (int kb = 0; kb < 8; ++kb) {
    int k0 = kb * 16 + 8 * h5;
    const short* wp = W + (((mb * 8 + kb) * 64 + lane) * 8);
    s16x8 ah = *(const s16x8*)wp;
    s16x8 al = *(const s16x8*)(wp + 32768);
    s16x8 bh = *(const s16x8*)(BH + brow * STR + k0);
    s16x8 bl = *(const s16x8*)(BH + LOFS + brow * STR + k0);
    acc = MFMA(ah, bh, acc);
    acc = MFMA(ah, bl, acc);
    acc = MFMA(al, bh, acc);
  }
}

// ---------------- weight preprocessing ----------------
__global__ __launch_bounds__(512)
void prep_kernel(const float* __restrict__ Wq, const float* __restrict__ Wk,
                 const float* __restrict__ Wvm, const float* __restrict__ Wvp,
                 const float* __restrict__ rp_W, short* __restrict__ ws) {
  int mid = blockIdx.x >> 2, hblk = blockIdx.x & 3;
  int kb = threadIdx.x >> 6, lane = threadIdx.x & 63;
  const float* src;
  if (mid < 4)       src = Wq  + mid * 16384;
  else if (mid < 8)  src = Wk  + (mid - 4) * 16384;
  else if (mid < 12) src = Wvm + (mid - 8) * 16384;
  else if (mid < 16) src = Wvp + (mid - 12) * 16384;
  else if (mid == 16) src = rp_W;
  else                src = rp_W + 16384;
  int h = hblk * 32 + (lane & 31);
  int kbase = kb * 16 + ((lane >> 5) << 3);
  s16x8 H, L;
  #pragma unroll
  for (int j = 0; j < 8; ++j) {
    float v = src[(size_t)(kbase + j) * 128 + h];
    unsigned short hi = bfhi(v);
    H[j] = (short)hi;
    L[j] = (short)bfhi(v - bf2f(hi));
  }
  short* dst = ws + (size_t)mid * 65536 + ((hblk * 8 + kb) * 64 + lane) * 8;
  *(s16x8*)dst = H;
  *(s16x8*)(dst + 32768) = L;
}

// ---------------- main kernel ----------------
__global__ __launch_bounds__(1024)
void cpt_kernel(const float* __restrict__ atom_types,
                const float* __restrict__ coords,
                const int*   __restrict__ edge_index,
                const float* __restrict__ edge_attr,
                const float* __restrict__ emb_Wm, const float* __restrict__ emb_bm,
                const float* __restrict__ emb_Wp, const float* __restrict__ emb_bp,
                const float* __restrict__ bq, const float* __restrict__ bk,
                const float* __restrict__ bvm, const float* __restrict__ bvp,
                const float* __restrict__ We,  const float* __restrict__ be,
                const float* __restrict__ dist_scale,
                const float* __restrict__ ln_g, const float* __restrict__ ln_b,
                const float* __restrict__ rp_b,
                const float* __restrict__ h1_W, const float* __restrict__ h1_b,
                const float* __restrict__ h2_W, const float* __restrict__ h2_b,
                const short* __restrict__ wpre,
                float* __restrict__ out)
{
  __shared__ __align__(16) short R1s[34816];
  __shared__ __align__(16) short R2s[34816];
  __shared__ float SCa[512];
  __shared__ float SCb[512];

  const int t = threadIdx.x, b = blockIdx.x;
  const int w = t >> 6, lane = t & 63, l31 = lane & 31, h5 = lane >> 5;
  const int mb = w >> 2, ncb = w & 3;
  const int mblk = mb << 5;
  const int nbase = ncb << 5;
  const float scale = 0.08838834764831845f;  // 1/sqrt(128)

  // ---- edge gather (one edge per thread; layer-invariant) ----
  int ef; float ebv[4];
  {
    int ei0 = edge_index[(size_t)b * 2048 + t];
    int ei1 = edge_index[(size_t)b * 2048 + 1024 + t];
    ef = ei0 * STR + ei1;
    float4 ea = *(const float4*)(edge_attr + ((size_t)b * 1024 + t) * 4);
    #pragma unroll
    for (int l = 0; l < 4; ++l)
      ebv[l] = ea.x * We[l*4+0] + ea.y * We[l*4+1] + ea.z * We[l*4+2] +
               ea.w * We[l*4+3] + be[l] + dist_scale[l] * ea.x;
  }

  // ---- embedding -> magP/phP (one tile: rows mblk+ROWP(reg), col nbase+l31) ----
  float magP[16], phP[16];
  {
    int hcol = nbase + l31;
    float wmv[19], wpv[19];
    #pragma unroll
    for (int d = 0; d < 19; ++d) {
      wmv[d] = emb_Wm[d * 128 + hcol];
      wpv[d] = emb_Wp[d * 128 + hcol];
    }
    float bm = emb_bm[hcol], bp = emb_bp[hcol];
    #pragma unroll
    for (int reg = 0; reg < 16; ++reg) {
      int a = mblk + ROWP(reg);
      const float* xr = atom_types + ((size_t)b * 128 + a) * 16;
      float x[19];
      float4 v0 = *(const float4*)xr,       v1 = *(const float4*)(xr + 4);
      float4 v2 = *(const float4*)(xr + 8), v3 = *(const float4*)(xr + 12);
      x[0]=v0.x; x[1]=v0.y; x[2]=v0.z; x[3]=v0.w;
      x[4]=v1.x; x[5]=v1.y; x[6]=v1.z; x[7]=v1.w;
      x[8]=v2.x; x[9]=v2.y; x[10]=v2.z; x[11]=v2.w;
      x[12]=v3.x; x[13]=v3.y; x[14]=v3.z; x[15]=v3.w;
      const float* cr = coords + ((size_t)b * 128 + a) * 3;
      x[16]=cr[0]; x[17]=cr[1]; x[18]=cr[2];
      float m0 = bm, p0 = bp;
      #pragma unroll
      for (int d = 0; d < 19; ++d) { m0 += x[d] * wmv[d]; p0 += x[d] * wpv[d]; }
      magP[reg] = m0; phP[reg] = p0;
    }
  }

  // ---- layers ----
  for (int l = 0; l < 4; ++l) {
    const short* wqP  = wpre + (size_t)l * 65536;
    const short* wkP  = wpre + (size_t)(4 + l) * 65536;
    const short* wvmP = wpre + (size_t)(8 + l) * 65536;
    const short* wvpP = wpre + (size_t)(12 + l) * 65536;

    __syncthreads();                       // prior readers of R1/R2 done
    float* biasF = (float*)R1s;            // fp32 [128][STR] bias matrix
    {
      float4* z4 = (float4*)R1s;
      #pragma unroll
      for (int k = 0; k < 5; ++k) { int idx = t + 1024 * k; if (idx < 4352) z4[idx] = make_float4(0.f,0.f,0.f,0.f); }
    }
    __syncthreads();
    atomicAdd(&biasF[ef], ebv[l]);         // edge-bias scatter
    __syncthreads();
    // preload scores acc with bias (scoresT: m=j=mblk+ROWP, n=i=nbase+l31)
    f32x16 accS;
    {
      int i = nbase + l31;
      #pragma unroll
      for (int reg = 0; reg < 16; ++reg)
        accS[reg] = biasF[i * STR + (mblk + ROWP(reg))];
    }
    __syncthreads();                       // bias reads done
    stageScatter(R1s, magP, ncb, l31, h5, mblk);   // mag -> R1 [a][h]
    __syncthreads();

    // Q^T (D[h][i]) -> R2 scaled; then K^T (D[h][j])
    {
      f32x16 accQ;
      #pragma unroll
      for (int reg = 0; reg < 16; ++reg) accQ[reg] = bq[l * 128 + mblk + ROWP(reg)];
      gemmTW(accQ, wqP, R1s, mb, ncb, l31, h5, lane);
      stageB64(R2s, accQ, ncb, l31, h5, mblk, scale);  // (scale*Q)[i][h] -> R2
    }
    f32x16 accK;
    #pragma unroll
    for (int reg = 0; reg < 16; ++reg) accK[reg] = bk[l * 128 + mblk + ROWP(reg)];
    gemmTW(accK, wkP, R1s, mb, ncb, l31, h5, lane);
    __syncthreads();                       // mag reads + Q writes done
    stageB64(R1s, accK, ncb, l31, h5, mblk, 1.0f);   // K[j][h] -> R1 (over mag)
    __syncthreads();

    // scoresT[j][i] = K @ (scale*Q)^T + bias
    gemmLL(accS, R1s, R2s, mblk, ncb, l31, h5);

    // softmax over j (16 regs + h5 partner + 4 mb waves)
    {
      float m = accS[0];
      #pragma unroll
      for (int reg = 1; reg < 16; ++reg) m = fmaxf(m, accS[reg]);
      m = fmaxf(m, __shfl_xor(m, 32));
      if (h5 == 0) SCa[mb * 128 + nbase + l31] = m;
    }
    __syncthreads();
    {
      int i = nbase + l31;
      float mg = fmaxf(fmaxf(SCa[i], SCa[128 + i]), fmaxf(SCa[256 + i], SCa[384 + i]));
      float s = 0.f;
      #pragma unroll
      for (int reg = 0; reg < 16; ++reg) {
        float e = __expf(accS[reg] - mg);
        accS[reg] = e; s += e;
      }
      s += __shfl_xor(s, 32);
      if (h5 == 0) SCb[mb * 128 + i] = s;
    }
    __syncthreads();
    {
      int i = nbase + l31;
      float sg = SCb[i] + SCb[128 + i] + SCb[256 + i] + SCb[384 + i];
      float inv = 1.f / sg;
      #pragma unroll
      for (int reg = 0; reg < 16; ++reg) accS[reg] *= inv;
    }
    __syncthreads();                       // scores reads of R1/R2 done
    stageB64(R2s, accS, ncb, l31, h5, mblk, 1.0f);   // attn[i][j] -> R2 (over Q)
    stageScatter(R1s, magP, ncb, l31, h5, mblk);     // mag -> R1 (over K)
    __syncthreads();

    // vm = mag @ Wvm
    {
      f32x16 accVM;
      float bv = bvm[l * 128 + nbase + l31];
      #pragma unroll
      for (int reg = 0; reg < 16; ++reg) accVM[reg] = bv;
      gemmNW(accVM, R1s, wvmP, mblk, ncb, l31, h5, lane);
      __syncthreads();                     // mag reads done
      stageB64(R1s, accVM, ncb, l31, h5, mblk, 1.0f);  // vmT[h][j] -> R1
      __syncthreads();
    }

    // new_mag = attn @ vm + mag
    f32x16 accM;
    #pragma unroll
    for (int reg = 0; reg < 16; ++reg) accM[reg] = magP[reg];
    gemmLL(accM, R2s, R1s, mblk, ncb, l31, h5);

    // LayerNorm over h (cols): shfl over l31, combine 4 ncb waves via SCa/SCb
    {
      float sv[16], qv[16];
      #pragma unroll
      for (int reg = 0; reg < 16; ++reg) {
        float a0 = accM[reg];
        float s = a0, q = a0 * a0;
        #pragma unroll
        for (int off = 1; off < 32; off <<= 1) { s += __shfl_xor(s, off); q += __shfl_xor(q, off); }
        sv[reg] = s; qv[reg] = q;
      }
      if (l31 == 0) {
        #pragma unroll
        for (int reg = 0; reg < 16; ++reg) {
          SCa[ncb * 128 + mblk + ROWP(reg)] = sv[reg];
          SCb[ncb * 128 + mblk + ROWP(reg)] = qv[reg];
        }
      }
      __syncthreads();
      float g0 = ln_g[l * 128 + nbase + l31], lb0 = ln_b[l * 128 + nbase + l31];
      #pragma unroll
      for (int reg = 0; reg < 16; ++reg) {
        int a = mblk + ROWP(reg);
        float s = SCa[a] + SCa[128 + a] + SCa[256 + a] + SCa[384 + a];
        float q = SCb[a] + SCb[128 + a] + SCb[256 + a] + SCb[384 + a];
        float mu = s * (1.f / 128.f);
        float var = q * (1.f / 128.f) - mu * mu;
        float inv = 1.f / sqrtf(var + 1e-5f);
        magP[reg] = g0 * ((accM[reg] - mu) * inv) + lb0;
      }
    }
    __syncthreads();                       // vm reads of R1 done
    stageScatter(R1s, phP, ncb, l31, h5, mblk);      // ph[a][h] -> R1
    __syncthreads();

    // vp = ph @ Wvp
    {
      f32x16 accV;
      float bv = bvp[l * 128 + nbase + l31];
      #pragma unroll
      for (int reg = 0; reg < 16; ++reg) accV[reg] = bv;
      gemmNW(accV, R1s, wvpP, mblk, ncb, l31, h5, lane);
      __syncthreads();                     // ph reads done
      stageB64(R1s, accV, ncb, l31, h5, mblk, 1.0f); // vpT[h][j] -> R1
      __syncthreads();
    }

    // new_ph = attn @ vp + ph
    f32x16 accP;
    #pragma unroll
    for (int reg = 0; reg < 16; ++reg) accP[reg] = phP[reg];
    gemmLL(accP, R2s, R1s, mblk, ncb, l31, h5);
    #pragma unroll
    for (int reg = 0; reg < 16; ++reg) phP[reg] = accP[reg];
  } // layers

  // ---- real/imag -> RealProjection ----
  float reB[16], imB[16];
  #pragma unroll
  for (int i = 0; i < 16; ++i) {
    float s_, c_;
    __sincosf(phP[i], &s_, &c_);
    reB[i] = magP[i] * c_;
    imB[i] = magP[i] * s_;
  }
  __syncthreads();
  stageScatter(R1s, reB, ncb, l31, h5, mblk);
  stageScatter(R2s, imB, ncb, l31, h5, mblk);
  __syncthreads();
  f32x16 accR;
  {
    float bv = rp_b[nbase + l31];
    #pragma unroll
    for (int reg = 0; reg < 16; ++reg) accR[reg] = bv;
  }
  gemmNW(accR, R1s, wpre + (size_t)16 * 65536, mblk, ncb, l31, h5, lane);  // real @ rpA
  gemmNW(accR, R2s, wpre + (size_t)17 * 65536, mblk, ncb, l31, h5, lane);  // imag @ rpB

  // ---- pooling (column sum over atoms) ----
  {
    float ps = 0.f;
    #pragma unroll
    for (int reg = 0; reg < 16; ++reg) ps += accR[reg];
    ps += __shfl_xor(ps, 32);
    if (h5 == 0) SCa[mb * 128 + nbase + l31] = ps;
  }
  __syncthreads();
  if (t < 128) {
    float cs = SCa[t] + SCa[128 + t] + SCa[256 + t] + SCa[384 + t];
    SCb[t] = cs;
  }
  __syncthreads();
  if (t < 128) {
    float acc = h1_b[t];
    for (int i = 0; i < 128; ++i) {
      float cs = SCb[i];
      acc += cs * (h1_W[(size_t)i * 128 + t] * (1.f / 128.f) +
                   h1_W[(size_t)(128 + i) * 128 + t]);
    }
    float hv = acc / (1.f + __expf(-acc));   // SiLU
    SCb[128 + t] = hv * h2_W[t];
  }
  __syncthreads();
  if (t < 64) {
    float s2 = SCb[128 + t] + SCb[192 + t];
    #pragma unroll
    for (int off = 32; off >= 1; off >>= 1) s2 += __shfl_xor(s2, off);
    if (t == 0) out[b] = s2 + h2_b[0];
  }
}

extern "C" void kernel_launch(void* const* d_in, const int* in_sizes, int n_in,
                              void* d_out, int out_size, void* d_ws, size_t ws_size,
                              hipStream_t stream) {
  const float* atom_types = (const float*)d_in[0];
  const float* coords     = (const float*)d_in[1];
  const int*   edge_index = (const int*)  d_in[2];
  const float* edge_attr  = (const float*)d_in[3];
  const float* emb_Wm = (const float*)d_in[4];
  const float* emb_bm = (const float*)d_in[5];
  const float* emb_Wp = (const float*)d_in[6];
  const float* emb_bp = (const float*)d_in[7];
  const float* Wq  = (const float*)d_in[8];
  const float* bq  = (const float*)d_in[9];
  const float* Wk  = (const float*)d_in[10];
  const float* bk  = (const float*)d_in[11];
  const float* Wvm = (const float*)d_in[12];
  const float* bvm = (const float*)d_in[13];
  const float* Wvp = (const float*)d_in[14];
  const float* bvp = (const float*)d_in[15];
  const float* We  = (const float*)d_in[16];
  const float* be  = (const float*)d_in[17];
  const float* dist_scale = (const float*)d_in[18];
  const float* ln_g = (const float*)d_in[19];
  const float* ln_b = (const float*)d_in[20];
  const float* rp_W = (const float*)d_in[21];
  const float* rp_b = (const float*)d_in[22];
  const float* h1_W = (const float*)d_in[23];
  const float* h1_b = (const float*)d_in[24];
  const float* h2_W = (const float*)d_in[25];
  const float* h2_b = (const float*)d_in[26];
  float* out = (float*)d_out;
  short* wpre = (short*)d_ws;   // 18 matrices * 65536 shorts = 2.36 MB

  hipLaunchKernelGGL(prep_kernel, dim3(72), dim3(512), 0, stream,
                     Wq, Wk, Wvm, Wvp, rp_W, wpre);
  hipLaunchKernelGGL(cpt_kernel, dim3(1024), dim3(1024), 0, stream,
                     atom_types, coords, edge_index, edge_attr,
                     emb_Wm, emb_bm, emb_Wp, emb_bp,
                     bq, bk, bvm, bvp,
                     We, be, dist_scale, ln_g, ln_b,
                     rp_b, h1_W, h1_b, h2_W, h2_b,
                     (const short*)wpre, out);
}

// Round 8
// 909.875 us; speedup vs baseline: 1.3202x; 1.2129x over previous
//
#include <hip/hip_runtime.h>
#include <math.h>

// ComplexPolarTransformerBeta — round 8: 256-thread blocks to get a 256-VGPR
// allocator target (measured law: target = 65536/blockDim; 512->128, 1024->64).
// 4 waves, wave w owns the 32-row block mblk=32w of every GEMM; tt=0..3 loops
// the 32-col tiles (4 independent MFMA chains/kb). Persistent mag/ph held in
// TRANSPOSED C-layout (h=32w+ROWP, a=32tt+l31) so all staging is packed b64.
// Bias matrix lives in a 16KB LDS quarter-buffer (4 passes) so accS never
// coexists with accQ/accK. Embedding done via MFMA (x staged to LDS, emb
// weights frag-prepped). LDS: 2x69.6K regions + 16K bias + 4K scratch = 159.7K.

typedef __attribute__((ext_vector_type(8)))  short s16x8;
typedef __attribute__((ext_vector_type(16))) float f32x16;

#define STR  136      // LDS row stride (shorts): 128 data + 8 pad
#define LOFS 17408    // lo-plane offset within a region (shorts)
#define MFMA(a, b, c) __builtin_amdgcn_mfma_f32_32x32x16_bf16(a, b, c, 0, 0, 0)
#define ROWP(reg) (((reg) & 3) + (((reg) >> 2) << 3) + (h5 << 2))

__device__ __forceinline__ unsigned short bfhi(float x) {
  unsigned u = __float_as_uint(x);
  return (unsigned short)((u + 0x7FFFu + ((u >> 16) & 1u)) >> 16);
}
__device__ __forceinline__ float bf2f(unsigned short h) {
  return __uint_as_float(((unsigned)h) << 16);
}

// Stage one C-layout tile into S[row][colbase + 8q + 4h5] as bf16 hi/lo (b64).
__device__ __forceinline__ void stageB64(short* SH, const f32x16& acc, int row,
                                         int colbase, int h5, float scl) {
  #pragma unroll
  for (int q = 0; q < 4; ++q) {
    int col = colbase + 8 * q + 4 * h5;
    float v0 = acc[4*q+0] * scl, v1 = acc[4*q+1] * scl;
    float v2 = acc[4*q+2] * scl, v3 = acc[4*q+3] * scl;
    unsigned short h0 = bfhi(v0), h1 = bfhi(v1), h2 = bfhi(v2), h3 = bfhi(v3);
    *(short4*)(SH + row * STR + col) = make_short4((short)h0,(short)h1,(short)h2,(short)h3);
    *(short4*)(SH + LOFS + row * STR + col) =
        make_short4((short)bfhi(v0 - bf2f(h0)), (short)bfhi(v1 - bf2f(h1)),
                    (short)bfhi(v2 - bf2f(h2)), (short)bfhi(v3 - bf2f(h3)));
  }
}

// acc[tt] += Wfrag(m-tile)^ * B(LDS rows 32tt+l31).  D[m=frag][n=LDS-row]
__device__ __forceinline__ void gemmTW4(f32x16* acc, const short* W, const short* BH,
                                        int mtile, int kbN, int l31, int h5, int lane) {
  #pragma unroll 1
  for (int kb = 0; kb < kbN; ++kb) {
    const short* wp = W + (((mtile * 8 + kb) * 64 + lane) * 8);
    s16x8 ah = *(const s16x8*)wp;
    s16x8 al = *(const s16x8*)(wp + 32768);
    int k0 = kb * 16 + 8 * h5;
    #pragma unroll
    for (int tt = 0; tt < 4; ++tt) {
      int brow = 32 * tt + l31;
      s16x8 bh = *(const s16x8*)(BH + brow * STR + k0);
      s16x8 bl = *(const s16x8*)(BH + LOFS + brow * STR + k0);
      acc[tt] = MFMA(ah, bh, acc[tt]);
      acc[tt] = MFMA(ah, bl, acc[tt]);
      acc[tt] = MFMA(al, bh, acc[tt]);
    }
  }
}

// acc[tt] += A(LDS rows mblk+l31) * Wfrag(n-tile=tt).  D[m=LDS-row][n=frag]
__device__ __forceinline__ void gemmNW4(f32x16* acc, const short* AH, const short* W,
                                        int mblk, int l31, int h5, int lane) {
  int arow = mblk + l31;
  #pragma unroll 1
  for (int kb = 0; kb < 8; ++kb) {
    int k0 = kb * 16 + 8 * h5;
    s16x8 ah = *(const s16x8*)(AH + arow * STR + k0);
    s16x8 al = *(const s16x8*)(AH + LOFS + arow * STR + k0);
    #pragma unroll
    for (int tt = 0; tt < 4; ++tt) {
      const short* wp = W + (((tt * 8 + kb) * 64 + lane) * 8);
      s16x8 bh = *(const s16x8*)wp;
      s16x8 bl = *(const s16x8*)(wp + 32768);
      acc[tt] = MFMA(ah, bh, acc[tt]);
      acc[tt] = MFMA(ah, bl, acc[tt]);
      acc[tt] = MFMA(al, bh, acc[tt]);
    }
  }
}

// acc[tt] += A(LDS rows mblk+l31) * B(LDS rows 32tt+l31)^T.
__device__ __forceinline__ void gemmLL4(f32x16* acc, const short* AH, const short* BH,
                                        int mblk, int l31, int h5) {
  int arow = mblk + l31;
  #pragma unroll 1
  for (int kb = 0; kb < 8; ++kb) {
    int k0 = kb * 16 + 8 * h5;
    s16x8 ah = *(const s16x8*)(AH + arow * STR + k0);
    s16x8 al = *(const s16x8*)(AH + LOFS + arow * STR + k0);
    #pragma unroll
    for (int tt = 0; tt < 4; ++tt) {
      int brow = 32 * tt + l31;
      s16x8 bh = *(const s16x8*)(BH + brow * STR + k0);
      s16x8 bl = *(const s16x8*)(BH + LOFS + brow * STR + k0);
      acc[tt] = MFMA(ah, bh, acc[tt]);
      acc[tt] = MFMA(ah, bl, acc[tt]);
      acc[tt] = MFMA(al, bh, acc[tt]);
    }
  }
}

// ---------------- weight preprocessing: fp32 [k][h] -> frag-ordered bf16 hi/lo ----
__global__ __launch_bounds__(512)
void prep_kernel(const float* __restrict__ Wq, const float* __restrict__ Wk,
                 const float* __restrict__ Wvm, const float* __restrict__ Wvp,
                 const float* __restrict__ rp_W,
                 const float* __restrict__ emb_Wm, const float* __restrict__ emb_Wp,
                 short* __restrict__ ws) {
  int mid = blockIdx.x >> 2, hblk = blockIdx.x & 3;
  int kb = threadIdx.x >> 6, lane = threadIdx.x & 63;
  const float* src;
  int krows = 128;
  if (mid < 4)        src = Wq  + mid * 16384;
  else if (mid < 8)   src = Wk  + (mid - 4) * 16384;
  else if (mid < 12)  src = Wvm + (mid - 8) * 16384;
  else if (mid < 16)  src = Wvp + (mid - 12) * 16384;
  else if (mid == 16) src = rp_W;
  else if (mid == 17) src = rp_W + 16384;
  else if (mid == 18) { src = emb_Wm; krows = 19; }
  else                { src = emb_Wp; krows = 19; }
  int h = hblk * 32 + (lane & 31);
  int kbase = kb * 16 + ((lane >> 5) << 3);
  s16x8 H, L;
  #pragma unroll
  for (int j = 0; j < 8; ++j) {
    int k = kbase + j;
    float v = (k < krows) ? src[(size_t)k * 128 + h] : 0.f;
    unsigned short hi = bfhi(v);
    H[j] = (short)hi;
    L[j] = (short)bfhi(v - bf2f(hi));
  }
  short* dst = ws + (size_t)mid * 65536 + ((hblk * 8 + kb) * 64 + lane) * 8;
  *(s16x8*)dst = H;
  *(s16x8*)(dst + 32768) = L;
}

// ---------------- main kernel ----------------
__global__ __launch_bounds__(256, 2)
void cpt_kernel(const float* __restrict__ atom_types,
                const float* __restrict__ coords,
                const int*   __restrict__ edge_index,
                const float* __restrict__ edge_attr,
                const float* __restrict__ emb_bm, const float* __restrict__ emb_bp,
                const float* __restrict__ bq, const float* __restrict__ bk,
                const float* __restrict__ bvm, const float* __restrict__ bvp,
                const float* __restrict__ We,  const float* __restrict__ be,
                const float* __restrict__ dist_scale,
                const float* __restrict__ ln_g, const float* __restrict__ ln_b,
                const float* __restrict__ rp_b,
                const float* __restrict__ h1_W, const float* __restrict__ h1_b,
                const float* __restrict__ h2_W, const float* __restrict__ h2_b,
                const short* __restrict__ wpre,
                float* __restrict__ out)
{
  __shared__ __align__(16) short R1s[34816];
  __shared__ __align__(16) short R2s[34816];
  __shared__ float Pf[4096];     // bias quarter-matrix [128][32], col ^= (i&31)
  __shared__ float SCa[512];
  __shared__ float SCb[512];

  const int t = threadIdx.x, b = blockIdx.x;
  const int w = t >> 6, lane = t & 63, l31 = lane & 31, h5 = lane >> 5;
  const int mblk = w << 5;
  const float scale = 0.08838834764831845f;  // 1/sqrt(128)

  // ---- stage x (atom_types||coords, k padded to 32) into R1 as bf16 hi/lo ----
  if (t < 128) {
    const float* xr = atom_types + ((size_t)b * 128 + t) * 16;
    const float* cr = coords + ((size_t)b * 128 + t) * 3;
    float xv[19];
    float4 a0 = *(const float4*)xr,       a1 = *(const float4*)(xr + 4);
    float4 a2 = *(const float4*)(xr + 8), a3 = *(const float4*)(xr + 12);
    xv[0]=a0.x; xv[1]=a0.y; xv[2]=a0.z; xv[3]=a0.w;
    xv[4]=a1.x; xv[5]=a1.y; xv[6]=a1.z; xv[7]=a1.w;
    xv[8]=a2.x; xv[9]=a2.y; xv[10]=a2.z; xv[11]=a2.w;
    xv[12]=a3.x; xv[13]=a3.y; xv[14]=a3.z; xv[15]=a3.w;
    xv[16]=cr[0]; xv[17]=cr[1]; xv[18]=cr[2];
    #pragma unroll
    for (int k = 0; k < 32; ++k) {
      float v = (k < 19) ? xv[k] : 0.f;
      unsigned short hh = bfhi(v);
      R1s[t * STR + k] = (short)hh;
      R1s[LOFS + t * STR + k] = (short)bfhi(v - bf2f(hh));
    }
  }
  __syncthreads();

  // ---- embedding via MFMA: magT/phT (TRANSPOSED: h=32w+ROWP(reg), a=32tt+l31) ----
  f32x16 magT[4], phT[4];
  {
    #pragma unroll
    for (int reg = 0; reg < 16; ++reg) {
      float bm = emb_bm[32 * w + ROWP(reg)];
      float bp = emb_bp[32 * w + ROWP(reg)];
      #pragma unroll
      for (int tt = 0; tt < 4; ++tt) { magT[tt][reg] = bm; phT[tt][reg] = bp; }
    }
    gemmTW4(magT, wpre + (size_t)18 * 65536, R1s, w, 2, l31, h5, lane);
    gemmTW4(phT,  wpre + (size_t)19 * 65536, R1s, w, 2, l31, h5, lane);
  }

  // ---- layers ----
  for (int l = 0; l < 4; ++l) {
    const short* wqP  = wpre + (size_t)l * 65536;
    const short* wkP  = wpre + (size_t)(4 + l) * 65536;
    const short* wvmP = wpre + (size_t)(8 + l) * 65536;
    const short* wvpP = wpre + (size_t)(12 + l) * 65536;

    __syncthreads();                                 // prior readers done
    #pragma unroll
    for (int tt = 0; tt < 4; ++tt)
      stageB64(R1s, magT[tt], 32 * tt + l31, mblk, h5, 1.f);   // mag[a][h] -> R1
    __syncthreads();

    // Q^T (D[h][i]) -> R2 scaled; then K^T (D[h][j]) held in accK
    {
      f32x16 accQ[4];
      #pragma unroll
      for (int reg = 0; reg < 16; ++reg) {
        float bv = bq[l * 128 + 32 * w + ROWP(reg)];
        #pragma unroll
        for (int tt = 0; tt < 4; ++tt) accQ[tt][reg] = bv;
      }
      gemmTW4(accQ, wqP, R1s, w, 8, l31, h5, lane);
      #pragma unroll
      for (int tt = 0; tt < 4; ++tt)
        stageB64(R2s, accQ[tt], 32 * tt + l31, mblk, h5, scale);  // Qs[i][h] -> R2
    }
    f32x16 accK[4];
    #pragma unroll
    for (int reg = 0; reg < 16; ++reg) {
      float bv = bk[l * 128 + 32 * w + ROWP(reg)];
      #pragma unroll
      for (int tt = 0; tt < 4; ++tt) accK[tt][reg] = bv;
    }
    gemmTW4(accK, wkP, R1s, w, 8, l31, h5, lane);
    __syncthreads();                                 // all mag reads done
    #pragma unroll
    for (int tt = 0; tt < 4; ++tt)
      stageB64(R1s, accK[tt], 32 * tt + l31, mblk, h5, 1.f);    // K[j][h] -> R1
    __syncthreads();

    // edge bias -> accS via quarter-buffer passes (accS: m=j=32w+ROWP, n=i=32tt+l31)
    f32x16 accS[4];
    {
      int e0i[4], e1i[4]; float ebv[4];
      float w0 = We[l*4], w1 = We[l*4+1], w2 = We[l*4+2], w3 = We[l*4+3];
      float bel = be[l], dsl = dist_scale[l];
      #pragma unroll
      for (int k = 0; k < 4; ++k) {
        int e = t + 256 * k;
        e0i[k] = edge_index[(size_t)b * 2048 + e];
        e1i[k] = edge_index[(size_t)b * 2048 + 1024 + e];
        float4 ea = *(const float4*)(edge_attr + ((size_t)b * 1024 + e) * 4);
        ebv[k] = ea.x*w0 + ea.y*w1 + ea.z*w2 + ea.w*w3 + bel + dsl*ea.x;
      }
      #pragma unroll 1
      for (int p = 0; p < 4; ++p) {
        #pragma unroll
        for (int k = 0; k < 16; ++k) Pf[t + 256 * k] = 0.f;
        __syncthreads();
        #pragma unroll
        for (int k = 0; k < 4; ++k)
          if ((e1i[k] >> 5) == p)
            atomicAdd(&Pf[e0i[k] * 32 + ((e1i[k] & 31) ^ (e0i[k] & 31))], ebv[k]);
        __syncthreads();
        if (w == p) {
          #pragma unroll
          for (int tt = 0; tt < 4; ++tt) {
            int i = 32 * tt + l31;
            #pragma unroll
            for (int reg = 0; reg < 16; ++reg)
              accS[tt][reg] = Pf[i * 32 + (ROWP(reg) ^ l31)];
          }
        }
        __syncthreads();
      }
    }

    // scoresT[j][i] = K @ Qs^T + bias
    gemmLL4(accS, R1s, R2s, mblk, l31, h5);

    // softmax over j (regs + h5 partner + 4 waves via SCa/SCb)
    #pragma unroll
    for (int tt = 0; tt < 4; ++tt) {
      float m = accS[tt][0];
      #pragma unroll
      for (int reg = 1; reg < 16; ++reg) m = fmaxf(m, accS[tt][reg]);
      m = fmaxf(m, __shfl_xor(m, 32));
      if (h5 == 0) SCa[w * 128 + 32 * tt + l31] = m;
    }
    __syncthreads();
    #pragma unroll
    for (int tt = 0; tt < 4; ++tt) {
      int i = 32 * tt + l31;
      float mg = fmaxf(fmaxf(SCa[i], SCa[128 + i]), fmaxf(SCa[256 + i], SCa[384 + i]));
      float s = 0.f;
      #pragma unroll
      for (int reg = 0; reg < 16; ++reg) {
        float e = __expf(accS[tt][reg] - mg);
        accS[tt][reg] = e; s += e;
      }
      s += __shfl_xor(s, 32);
      if (h5 == 0) SCb[w * 128 + i] = s;
    }
    __syncthreads();
    #pragma unroll
    for (int tt = 0; tt < 4; ++tt) {
      int i = 32 * tt + l31;
      float sg = SCb[i] + SCb[128 + i] + SCb[256 + i] + SCb[384 + i];
      float inv = 1.f / sg;
      #pragma unroll
      for (int reg = 0; reg < 16; ++reg) accS[tt][reg] *= inv;
    }
    #pragma unroll
    for (int tt = 0; tt < 4; ++tt)
      stageB64(R2s, accS[tt], 32 * tt + l31, mblk, h5, 1.f);    // attn[i][j] -> R2
    #pragma unroll
    for (int tt = 0; tt < 4; ++tt)
      stageB64(R1s, magT[tt], 32 * tt + l31, mblk, h5, 1.f);    // mag[a][h] -> R1
    __syncthreads();

    // vm = mag @ Wvm (normal, D[j][h]); held, then staged as vmT[h][j]
    {
      f32x16 accVM[4];
      #pragma unroll
      for (int tt = 0; tt < 4; ++tt) {
        float bv = bvm[l * 128 + 32 * tt + l31];
        #pragma unroll
        for (int reg = 0; reg < 16; ++reg) accVM[tt][reg] = bv;
      }
      gemmNW4(accVM, R1s, wvmP, mblk, l31, h5, lane);
      __syncthreads();                               // all mag reads done
      #pragma unroll
      for (int tt = 0; tt < 4; ++tt)
        stageB64(R1s, accVM[tt], 32 * tt + l31, mblk, h5, 1.f); // vmT[h][j] -> R1
      __syncthreads();
    }

    // new_mag^T = vm^T @ attn^T + mag^T  (accM: h=32w+ROWP, i=32tt+l31)
    f32x16 accM[4];
    #pragma unroll
    for (int tt = 0; tt < 4; ++tt) accM[tt] = magT[tt];
    gemmLL4(accM, R1s, R2s, mblk, l31, h5);

    // LayerNorm over h: sum over regs + h5 partner + 4 waves
    {
      #pragma unroll
      for (int tt = 0; tt < 4; ++tt) {
        float s = 0.f, q = 0.f;
        #pragma unroll
        for (int reg = 0; reg < 16; ++reg) { float v = accM[tt][reg]; s += v; q += v*v; }
        s += __shfl_xor(s, 32); q += __shfl_xor(q, 32);
        if (h5 == 0) { SCa[w * 128 + 32 * tt + l31] = s; SCb[w * 128 + 32 * tt + l31] = q; }
      }
      __syncthreads();
      #pragma unroll
      for (int reg = 0; reg < 16; ++reg) {
        float gv = ln_g[l * 128 + 32 * w + ROWP(reg)];
        float bv = ln_b[l * 128 + 32 * w + ROWP(reg)];
        #pragma unroll
        for (int tt = 0; tt < 4; ++tt) {
          int i = 32 * tt + l31;
          float s = SCa[i] + SCa[128 + i] + SCa[256 + i] + SCa[384 + i];
          float q = SCb[i] + SCb[128 + i] + SCb[256 + i] + SCb[384 + i];
          float mu = s * (1.f / 128.f);
          float var = q * (1.f / 128.f) - mu * mu;
          float inv = 1.f / sqrtf(var + 1e-5f);
          magT[tt][reg] = gv * ((accM[tt][reg] - mu) * inv) + bv;
        }
      }
    }
    #pragma unroll
    for (int tt = 0; tt < 4; ++tt)
      stageB64(R1s, phT[tt], 32 * tt + l31, mblk, h5, 1.f);     // ph[a][h] -> R1
    __syncthreads();

    // vp = ph @ Wvp (normal); staged as vpT[h][j]
    {
      f32x16 accV[4];
      #pragma unroll
      for (int tt = 0; tt < 4; ++tt) {
        float bv = bvp[l * 128 + 32 * tt + l31];
        #pragma unroll
        for (int reg = 0; reg < 16; ++reg) accV[tt][reg] = bv;
      }
      gemmNW4(accV, R1s, wvpP, mblk, l31, h5, lane);
      __syncthreads();                               // all ph reads done
      #pragma unroll
      for (int tt = 0; tt < 4; ++tt)
        stageB64(R1s, accV[tt], 32 * tt + l31, mblk, h5, 1.f);  // vpT[h][j] -> R1
      __syncthreads();
    }

    // new_ph^T = vp^T @ attn^T + ph^T
    f32x16 accP[4];
    #pragma unroll
    for (int tt = 0; tt < 4; ++tt) accP[tt] = phT[tt];
    gemmLL4(accP, R1s, R2s, mblk, l31, h5);
    #pragma unroll
    for (int tt = 0; tt < 4; ++tt) phT[tt] = accP[tt];
  } // layers

  // ---- real/imag -> RealProjection (transposed accR: hout=32w+ROWP, a=32tt+l31) ----
  f32x16 reT[4], imT[4];
  #pragma unroll
  for (int tt = 0; tt < 4; ++tt)
    #pragma unroll
    for (int reg = 0; reg < 16; ++reg) {
      float s_, c_;
      __sincosf(phT[tt][reg], &s_, &c_);
      reT[tt][reg] = magT[tt][reg] * c_;
      imT[tt][reg] = magT[tt][reg] * s_;
    }
  __syncthreads();
  #pragma unroll
  for (int tt = 0; tt < 4; ++tt) {
    stageB64(R1s, reT[tt], 32 * tt + l31, mblk, h5, 1.f);   // re[a][h] -> R1
    stageB64(R2s, imT[tt], 32 * tt + l31, mblk, h5, 1.f);   // im[a][h] -> R2
  }
  __syncthreads();
  f32x16 accR[4];
  #pragma unroll
  for (int reg = 0; reg < 16; ++reg) {
    float bv = rp_b[32 * w + ROWP(reg)];
    #pragma unroll
    for (int tt = 0; tt < 4; ++tt) accR[tt][reg] = bv;
  }
  gemmTW4(accR, wpre + (size_t)16 * 65536, R1s, w, 8, l31, h5, lane);  // rpA^T @ re^T
  gemmTW4(accR, wpre + (size_t)17 * 65536, R2s, w, 8, l31, h5, lane);  // rpB^T @ im^T

  // ---- pooling: column sum over atoms a (tt in-thread + l31 shfl) ----
  {
    float cs[16];
    #pragma unroll
    for (int reg = 0; reg < 16; ++reg) {
      float s = accR[0][reg] + accR[1][reg] + accR[2][reg] + accR[3][reg];
      s += __shfl_xor(s, 16); s += __shfl_xor(s, 8);
      s += __shfl_xor(s, 4);  s += __shfl_xor(s, 2); s += __shfl_xor(s, 1);
      cs[reg] = s;
    }
    if (l31 == 0) {
      #pragma unroll
      for (int reg = 0; reg < 16; ++reg) SCa[32 * w + ROWP(reg)] = cs[reg];
    }
  }
  __syncthreads();
  if (t < 128) {
    float acc = h1_b[t];
    for (int i = 0; i < 128; ++i) {
      float c = SCa[i];
      acc += c * (h1_W[(size_t)i * 128 + t] * (1.f / 128.f) +
                  h1_W[(size_t)(128 + i) * 128 + t]);
    }
    float hv = acc / (1.f + __expf(-acc));   // SiLU
    SCb[t] = hv * h2_W[t];
  }
  __syncthreads();
  if (t < 64) {
    float s2 = SCb[t] + SCb[64 + t];
    #pragma unroll
    for (int off = 32; off >= 1; off >>= 1) s2 += __shfl_xor(s2, off);
    if (t == 0) out[b] = s2 + h2_b[0];
  }
}

extern "C" void kernel_launch(void* const* d_in, const int* in_sizes, int n_in,
                              void* d_out, int out_size, void* d_ws, size_t ws_size,
                              hipStream_t stream) {
  const float* atom_types = (const float*)d_in[0];
  const float* coords     = (const float*)d_in[1];
  const int*   edge_index = (const int*)  d_in[2];
  const float* edge_attr  = (const float*)d_in[3];
  const float* emb_Wm = (const float*)d_in[4];
  const float* emb_bm = (const float*)d_in[5];
  const float* emb_Wp = (const float*)d_in[6];
  const float* emb_bp = (const float*)d_in[7];
  const float* Wq  = (const float*)d_in[8];
  const float* bq  = (const float*)d_in[9];
  const float* Wk  = (const float*)d_in[10];
  const float* bk  = (const float*)d_in[11];
  const float* Wvm = (const float*)d_in[12];
  const float* bvm = (const float*)d_in[13];
  const float* Wvp = (const float*)d_in[14];
  const float* bvp = (const float*)d_in[15];
  const float* We  = (const float*)d_in[16];
  const float* be  = (const float*)d_in[17];
  const float* dist_scale = (const float*)d_in[18];
  const float* ln_g = (const float*)d_in[19];
  const float* ln_b = (const float*)d_in[20];
  const float* rp_W = (const float*)d_in[21];
  const float* rp_b = (const float*)d_in[22];
  const float* h1_W = (const float*)d_in[23];
  const float* h1_b = (const float*)d_in[24];
  const float* h2_W = (const float*)d_in[25];
  const float* h2_b = (const float*)d_in[26];
  float* out = (float*)d_out;
  short* wpre = (short*)d_ws;   // 20 matrices * 131072 B = 2.62 MB

  hipLaunchKernelGGL(prep_kernel, dim3(80), dim3(512), 0, stream,
                     Wq, Wk, Wvm, Wvp, rp_W, emb_Wm, emb_Wp, wpre);
  hipLaunchKernelGGL(cpt_kernel, dim3(1024), dim3(256), 0, stream,
                     atom_types, coords, edge_index, edge_attr,
                     emb_bm, emb_bp,
                     bq, bk, bvm, bvp,
                     We, be, dist_scale, ln_g, ln_b,
                     rp_b, h1_W, h1_b, h2_W, h2_b,
                     (const short*)wpre, out);
}